// Round 2
// baseline (106.739 us; speedup 1.0000x reference)
//
#include <hip/hip_runtime.h>

// Speculative-decode next-step input preparation.
// Per request r (R=8192), T = 1+SPEC = 8 tokens:
//   a        = clamp(accepted_num[r], 1, SC)
//   base     = input_positions[r*T] + a
//   pos[j]   = base + j
//   tok[0]   = sampled_tokens[r, a-1]; tok[j>0] = spec_tokens[r, j-1]
//   blk      = block_table[r, pos/block_size]
//   slot     = blk*block_size + pos%block_size
//   seq_len  = pos + 1
// Outputs concatenated flat: [tokens | pos | seq_lens | slots], each R*T int32.
//
// v3: token-parallel (1024 waves, whole chip) + dependent-chain trim.
//   - pos/bs division (a ~20-instr v_rcp_iflag sequence on the critical path
//     between first-level loads and the block_table gather) replaced with a
//     shift/mask fast path under a uniform pow2 branch (bs=128 in practice).
//   - token gather via single predicated address (no divergent two-path load).
// Measurement context (r1 rocprof): timed region is dominated by >=2 harness
// re-poison fills/iter, each 256 MiB at ~6.5 TB/s (81% HBM peak, i.e. at the
// fill roofline). Kernel slice is launch+latency floored (~10 us). This round
// is a falsification probe: if dur_us stays ~106 us, we are at the floor.

__global__ __launch_bounds__(256) void spec_prep_t8_tok_kernel(
    const int* __restrict__ input_positions,   // [R*8]
    const int* __restrict__ sampled_tokens,    // [R*8]  (SC==8)
    const int* __restrict__ block_table,       // [R*MAXB]
    const int* __restrict__ spec_tokens,       // [R*7]
    const int* __restrict__ accepted_num,      // [R]
    const int* __restrict__ block_size_p,      // [1]
    int* __restrict__ out,                     // [4*N]
    int MAXB, int N)
{
    const int idx = blockIdx.x * blockDim.x + threadIdx.x;
    if (idx >= N) return;
    const int j = idx & 7;
    const int r = idx >> 3;

    const int bs = *block_size_p;              // uniform s_load
    const int ls = 31 - __clz(bs);             // log2(bs) when pow2
    const bool pow2 = (bs & (bs - 1)) == 0;    // uniform branch

    // Independent first-level loads, issued up front.
    const int p     = input_positions[idx & ~7];   // 8 lanes/request same line
    const int a_raw = accepted_num[r];

    const int a = a_raw < 1 ? 1 : (a_raw > 8 ? 8 : a_raw);

    // token: single predicated-address gather (j==0 -> last accepted sample)
    const int* tok_ptr = (j == 0) ? (sampled_tokens + r * 8 + (a - 1))
                                  : (spec_tokens   + r * 7 + (j - 1));
    const int tok = *tok_ptr;

    // second-level: block table gather (concurrent with tok gather)
    const int pos = p + a + j;
    int d, rem, slot;
    if (pow2) {
        d    = pos >> ls;
        rem  = pos & (bs - 1);
        const int blk = block_table[(long)r * MAXB + d];
        slot = (blk << ls) | rem;
    } else {
        d    = pos / bs;
        rem  = pos - d * bs;
        const int blk = block_table[(long)r * MAXB + d];
        slot = blk * bs + rem;
    }

    out[idx]         = tok;
    out[N + idx]     = pos;
    out[2 * N + idx] = pos + 1;
    out[3 * N + idx] = slot;
}

// Generic fallback (any T): 1 thread per output element.
__global__ __launch_bounds__(256) void spec_prep_generic_kernel(
    const int* __restrict__ input_positions,
    const int* __restrict__ sampled_tokens,
    const int* __restrict__ block_table,
    const int* __restrict__ spec_tokens,
    const int* __restrict__ accepted_num,
    const int* __restrict__ block_size_p,
    int* __restrict__ out,
    int T, int SC, int SPEC, int MAXB, int N)
{
    int idx = blockIdx.x * blockDim.x + threadIdx.x;
    if (idx >= N) return;
    int r = idx / T;
    int j = idx - r * T;
    int bs = *block_size_p;
    int a = accepted_num[r];
    a = a < 1 ? 1 : (a > SC ? SC : a);
    int pos = input_positions[r * T] + a + j;
    int tok = (j == 0) ? sampled_tokens[r * SC + (a - 1)]
                       : spec_tokens[r * SPEC + (j - 1)];
    int blk = block_table[(long)r * MAXB + pos / bs];
    out[idx]         = tok;
    out[N + idx]     = pos;
    out[2 * N + idx] = pos + 1;
    out[3 * N + idx] = blk * bs + pos % bs;
}

extern "C" void kernel_launch(void* const* d_in, const int* in_sizes, int n_in,
                              void* d_out, int out_size, void* d_ws, size_t ws_size,
                              hipStream_t stream) {
    // setup_inputs() order:
    // 0 input_tokens (unused), 1 sampled_tokens [R*SC], 2 input_positions [R*T],
    // 3 seq_lens (unused), 4 slot_mapping (unused), 5 block_table [R*MAXB],
    // 6 spec_tokens [R*SPEC], 7 accepted_num [R], 8 num_seqs, 9 num_queries, 10 block_size
    const int* sampled_tokens  = (const int*)d_in[1];
    const int* input_positions = (const int*)d_in[2];
    const int* block_table     = (const int*)d_in[5];
    const int* spec_tokens     = (const int*)d_in[6];
    const int* accepted_num    = (const int*)d_in[7];
    const int* block_size_p    = (const int*)d_in[10];

    const int R    = in_sizes[7];
    const int N    = in_sizes[2];          // R*T
    const int T    = N / R;
    const int SC   = in_sizes[1] / R;
    const int SPEC = in_sizes[6] / R;
    const int MAXB = in_sizes[5] / R;

    int* out = (int*)d_out;

    if (T == 8 && SPEC == 7 && SC == 8) {
        const int block = 256;
        const int grid = (N + block - 1) / block;   // 256 workgroups, 1024 waves
        spec_prep_t8_tok_kernel<<<grid, block, 0, stream>>>(
            input_positions, sampled_tokens, block_table, spec_tokens,
            accepted_num, block_size_p, out, MAXB, N);
    } else {
        const int block = 256;
        const int grid = (N + block - 1) / block;
        spec_prep_generic_kernel<<<grid, block, 0, stream>>>(
            input_positions, sampled_tokens, block_table, spec_tokens,
            accepted_num, block_size_p, out, T, SC, SPEC, MAXB, N);
    }
}